// Round 13
// baseline (59.695 us; speedup 1.0000x reference)
//
#include <hip/hip_runtime.h>
#include <math.h>

// Problem constants
constexpr int BN  = 16;    // batch
constexpr int HH  = 224;
constexpr int WW  = 224;
constexpr int CI  = 8;     // input channels
constexpr int FF  = 256;   // filter feature dim
constexpr int NC  = 16;    // output channels
constexpr int NP  = 1152;  // CI*NC*3*3 dynamic params per sample
// reference patch index p = cin*9 + dy*3 + dx ; w[b][p][c] = dyn[b][p*16+c]
// MFMA K-ordering: k = tap*8 + cin, tap = dy*3+dx (taps 9..11 pad=0)

typedef __attribute__((ext_vector_type(8))) short short8;   // 8 bf16 = 4 VGPR
typedef __attribute__((ext_vector_type(4))) float f32x4;

__device__ __forceinline__ float elu_f(float x) {
    return x > 0.0f ? x : (__expf(x) - 1.0f);
}

// split f32 -> bf16 hi (truncate) + bf16 lo (residual, truncate): v ~= hi+lo
__device__ __forceinline__ void split8(const float* v, short8& hi, short8& lo) {
#pragma unroll
    for (int j = 0; j < 8; ++j) {
        const unsigned u = __float_as_uint(v[j]);
        hi[j] = (short)(u >> 16);
        const float hf = __uint_as_float(u & 0xffff0000u);
        lo[j] = (short)(__float_as_uint(v[j] - hf) >> 16);
    }
}

// ------ fused kernel 1+2: per-block h-slice + dyn/bias partial atomics -------
// grid 72 blocks = 9 col-groups (128 cols) x 8 k-splits (32 k), 128 threads.
// Phase 1: block computes hs[16][32] = elu(fi@W1+b1) for its own k-slice
//   (fi staged in LDS; thread t owns k = k0+(t&31), samples rg*4..rg*4+3).
// Phase 2 (r12-proven): each thread owns one Wd column; per k ONE coalesced
//   Wd load feeds 16 FMAs. Pure partials atomicAdd'ed into zeroed buffers;
//   bd / bb+dfn are folded in later by k_conv's B-setup.
__global__ __launch_bounds__(128) void k_dynf(const float* __restrict__ fi,
                                              const float* __restrict__ W1,
                                              const float* __restrict__ b1,
                                              const float* __restrict__ Wd,
                                              const float* __restrict__ Wb,
                                              float* __restrict__ w_out,
                                              float* __restrict__ bias_out) {
    __shared__ float fis[BN][FF];            // 16 KB
    __shared__ float hs[BN][32];             // 2 KB
    const int bid = blockIdx.x;
    const int cg  = bid % 9;                 // column group (128 cols)
    const int ks  = bid / 9;                 // k-split (32 k)
    const int k0  = ks * 32;
    const int t   = threadIdx.x;

    // stage fi (16x256 floats) as float4, coalesced
#pragma unroll
    for (int e = 0; e < 8; ++e) {
        const int q = e * 128 + t;           // 0..1023 float4s
        ((float4*)fis)[q] = ((const float4*)fi)[q];
    }
    __syncthreads();

    // ---- phase 1: h slice ----
    {
        const int kk = t & 31, rg = t >> 5;  // rg 0..3 -> samples rg*4..rg*4+3
        float hacc[4];
#pragma unroll
        for (int r = 0; r < 4; ++r) hacc[r] = b1[k0 + kk];
#pragma unroll 8
        for (int j = 0; j < FF; ++j) {
            const float w1 = W1[j * FF + k0 + kk];
#pragma unroll
            for (int r = 0; r < 4; ++r)
                hacc[r] = fmaf(fis[rg * 4 + r][j], w1, hacc[r]);
        }
#pragma unroll
        for (int r = 0; r < 4; ++r) hs[rg * 4 + r][kk] = elu_f(hacc[r]);
    }
    __syncthreads();

    // ---- phase 2: dyn partials ----
    const int i = cg * 128 + t;              // output column < 1152
    float a[16];
#pragma unroll
    for (int b = 0; b < 16; ++b) a[b] = 0.0f;

#pragma unroll 8
    for (int kk = 0; kk < 32; ++kk) {
        const float w = Wd[(size_t)(k0 + kk) * NP + i];
#pragma unroll
        for (int b = 0; b < 16; ++b) a[b] = fmaf(hs[b][kk], w, a[b]);
    }
#pragma unroll
    for (int b = 0; b < 16; ++b) atomicAdd(&w_out[b * NP + i], a[b]);

    if (cg == 0) {                           // bias partials ride along here
#pragma unroll
        for (int r = 0; r < 2; ++r) {
            const int p = t + r * 128;       // 0..255
            const int b = p >> 4, c = p & 15;
            float s = 0.0f;
#pragma unroll 8
            for (int kk = 0; kk < 32; ++kk)
                s = fmaf(hs[b][kk], Wb[(size_t)(k0 + kk) * NC + c], s);
            atomicAdd(&bias_out[b * NC + c], s);
        }
    }
}

// ---------------- kernel 3: dynamic conv as per-sample MFMA GEMM -------------
// Round-8 validated body + 2x grid split + THREE independent accumulator
// chains (accM=hi*hi, accL=lo*hi, accH=hi*lo) so the dependent MFMA chain per
// tile is 3-deep, not 6. B-setup folds in bd (weights) and bb+dfn (bias)
// since k_dynf now produces pure partials.
// mfma_f32_16x16x32_bf16 layouts (lane l):
//   A: row = l&15 (pixel), k = (l>>4)*8 + i  -> one 32B NHWC load per chunk
//   B: col = l&15 (channel), k = (l>>4)*8+i  -> loaded once per wave (24 regs)
//   C: col = l&15 (channel), row = (l>>4)*4 + r (pixel)
__global__ __launch_bounds__(128) void k_conv(const float* __restrict__ in,
                                              const float* __restrict__ w_all,
                                              const float* __restrict__ bias_all,
                                              const float* __restrict__ bd,
                                              const float* __restrict__ bb,
                                              const float* __restrict__ dfn,
                                              float* __restrict__ out) {
    const int b    = blockIdx.z;
    const int half = blockIdx.x;       // 0/1: tiles 0-6 or 7-13
    const int t    = threadIdx.x;
    const int wid  = t >> 6;
    const int lane = t & 63;
    const int cl   = lane & 15;        // A-row pixel idx / B,C channel idx
    const int g    = lane >> 4;        // k-group 0..3
    const int y    = blockIdx.y * 2 + wid;

    // ---- per-lane tap geometry for the 3 k-chunks ----
    int  dyL[3], dxL[3];
    bool real[3];
#pragma unroll
    for (int c = 0; c < 3; ++c) {
        const int tap = c * 4 + g;
        real[c] = (tap < 9);
        const int tp = real[c] ? tap : 0;
        dyL[c] = tp / 3;
        dxL[c] = tp - 3 * dyL[c];
    }

    // ---- B fragments (hi/lo), loaded once per wave; + bd fold-in ----
    const float* __restrict__ wq = w_all + b * NP;
    short8 bhi0, blo0, bhi1, blo1, bhi2, blo2;
    {
        float wv[8];
#pragma unroll
        for (int i = 0; i < 8; ++i) {
            const int idx = (i * 9 + (0 * 4 + g)) * NC + cl;
            wv[i] = real[0] ? (wq[idx] + bd[idx]) : 0.0f;
        }
        split8(wv, bhi0, blo0);
#pragma unroll
        for (int i = 0; i < 8; ++i) {
            const int idx = (i * 9 + (1 * 4 + g)) * NC + cl;
            wv[i] = real[1] ? (wq[idx] + bd[idx]) : 0.0f;
        }
        split8(wv, bhi1, blo1);
#pragma unroll
        for (int i = 0; i < 8; ++i) {
            const int idx = (i * 9 + (2 * 4 + g)) * NC + cl;
            wv[i] = real[2] ? (wq[idx] + bd[idx]) : 0.0f;
        }
        split8(wv, bhi2, blo2);
    }

    // ---- per-chunk input row base + validity ----
    size_t ro[3];
    bool   okr[3];
#pragma unroll
    for (int c = 0; c < 3; ++c) {
        const int iy = y + dyL[c] - 1;
        okr[c] = real[c] && ((unsigned)iy < (unsigned)HH);
        const int iyc = min(max(iy, 0), HH - 1);
        ro[c] = ((size_t)(b * HH + iyc) * WW) * CI;
    }

    const float bias = bias_all[b * NC + cl] + bb[cl] + dfn[cl];
    const size_t orow = ((size_t)(b * HH + y) * WW) * NC;

#pragma unroll 1
    for (int tx = 0; tx < 7; ++tx) {
        const int x0 = (half * 7 + tx) * 16;
        f32x4 accM = {bias, bias, bias, bias};   // hi*hi
        f32x4 accL = {0.f, 0.f, 0.f, 0.f};       // lo*hi
        f32x4 accH = {0.f, 0.f, 0.f, 0.f};       // hi*lo

#pragma unroll
        for (int c = 0; c < 3; ++c) {
            const int  ix = x0 + cl + dxL[c] - 1;
            const bool ok = okr[c] && ((unsigned)ix < (unsigned)WW);
            const int  ixc = min(max(ix, 0), WW - 1);
            const float4* pp = (const float4*)(in + ro[c] + (size_t)ixc * CI);
            const float4 a0 = pp[0];
            const float4 a1 = pp[1];
            float av[8];
            av[0] = ok ? a0.x : 0.0f;
            av[1] = ok ? a0.y : 0.0f;
            av[2] = ok ? a0.z : 0.0f;
            av[3] = ok ? a0.w : 0.0f;
            av[4] = ok ? a1.x : 0.0f;
            av[5] = ok ? a1.y : 0.0f;
            av[6] = ok ? a1.z : 0.0f;
            av[7] = ok ? a1.w : 0.0f;
            short8 ahi, alo;
            split8(av, ahi, alo);
            const short8 bh = (c == 0) ? bhi0 : (c == 1) ? bhi1 : bhi2;
            const short8 bl = (c == 0) ? blo0 : (c == 1) ? blo1 : blo2;
            accM = __builtin_amdgcn_mfma_f32_16x16x32_bf16(ahi, bh, accM, 0, 0, 0);
            accL = __builtin_amdgcn_mfma_f32_16x16x32_bf16(alo, bh, accL, 0, 0, 0);
            accH = __builtin_amdgcn_mfma_f32_16x16x32_bf16(ahi, bl, accH, 0, 0, 0);
        }

        // ---- epilogue: elu + store (lane cl = channel, rows g*4+r = pixel) --
#pragma unroll
        for (int r = 0; r < 4; ++r) {
            const int px = g * 4 + r;
            out[orow + (size_t)(x0 + px) * NC + cl] =
                elu_f(accM[r] + accL[r] + accH[r]);
        }
    }
}

extern "C" void kernel_launch(void* const* d_in, const int* in_sizes, int n_in,
                              void* d_out, int out_size, void* d_ws, size_t ws_size,
                              hipStream_t stream) {
    const float* inpt = (const float*)d_in[0];
    const float* fi   = (const float*)d_in[1];
    const float* W1   = (const float*)d_in[2];
    const float* b1   = (const float*)d_in[3];
    const float* Wd   = (const float*)d_in[4];
    const float* bd   = (const float*)d_in[5];
    const float* Wb   = (const float*)d_in[6];
    const float* bb   = (const float*)d_in[7];
    const float* dfn  = (const float*)d_in[8];
    float* out = (float*)d_out;

    float* ws    = (float*)d_ws;
    float* wDyn  = ws + 4096;             // 16*1152 = 18432 floats (partials)
    float* biasA = ws + 4096 + 18432;     // 16*16   = 256 floats  (partials)

    // zero the atomic-accumulation region (wDyn + biasA are contiguous)
    hipMemsetAsync(wDyn, 0, (size_t)(BN * NP + BN * NC) * sizeof(float), stream);

    k_dynf<<<72, 128, 0, stream>>>(fi, W1, b1, Wd, Wb, wDyn, biasA);
    k_conv<<<dim3(2, 112, BN), 128, 0, stream>>>(inpt, wDyn, biasA,
                                                 bd, bb, dfn, out);
}

// Round 14
// 46.093 us; speedup vs baseline: 1.2951x; 1.2951x over previous
//
#include <hip/hip_runtime.h>
#include <math.h>

// Problem constants
constexpr int BN  = 16;    // batch
constexpr int HH  = 224;
constexpr int WW  = 224;
constexpr int CI  = 8;     // input channels
constexpr int FF  = 256;   // filter feature dim
constexpr int NC  = 16;    // output channels
constexpr int NP  = 1152;  // CI*NC*3*3 dynamic params per sample
// reference patch index p = cin*9 + dy*3 + dx ; w[b][p][c] = dyn[b][p*16+c]
// MFMA K-ordering: k = tap*8 + cin, tap = dy*3+dx (taps 9..11 pad=0)

typedef __attribute__((ext_vector_type(8))) short short8;   // 8 bf16 = 4 VGPR
typedef __attribute__((ext_vector_type(4))) float f32x4;

__device__ __forceinline__ float elu_f(float x) {
    return x > 0.0f ? x : (__expf(x) - 1.0f);
}

// split f32 -> bf16 hi (truncate) + bf16 lo (residual, truncate): v ~= hi+lo
__device__ __forceinline__ void split8(const float* v, short8& hi, short8& lo) {
#pragma unroll
    for (int j = 0; j < 8; ++j) {
        const unsigned u = __float_as_uint(v[j]);
        hi[j] = (short)(u >> 16);
        const float hf = __uint_as_float(u & 0xffff0000u);
        lo[j] = (short)(__float_as_uint(v[j] - hf) >> 16);
    }
}

// ---------------- kernel 1: h = elu(filter_inpt @ W1 + b1) -------------------
// grid 32 blocks (16 samples x 2 halves), 128 threads. Also initializes
// w_out (=bd) and bias_out (=bb+dfn) for k_dyn's atomic k-split accumulation
// (stream order guarantees init completes before k_dyn's atomics).
__global__ __launch_bounds__(128) void k_h(const float* __restrict__ fi,
                                           const float* __restrict__ W1,
                                           const float* __restrict__ b1,
                                           const float* __restrict__ bd,
                                           const float* __restrict__ bb,
                                           const float* __restrict__ dfn,
                                           float* __restrict__ h_out,
                                           float* __restrict__ w_out,
                                           float* __restrict__ bias_out) {
    __shared__ float x[FF];
    int bid = blockIdx.x;
    int b = bid >> 1, half = bid & 1;
    int t = threadIdx.x;
    x[t]       = fi[b * FF + t];
    x[t + 128] = fi[b * FF + t + 128];
    __syncthreads();
    int col = half * 128 + t;
    float acc = b1[col];
#pragma unroll 8
    for (int k = 0; k < FF; ++k) acc = fmaf(x[k], W1[k * FF + col], acc);
    h_out[b * FF + col] = elu_f(acc);

    // ---- init for k_dyn atomics (grid-stride over 16*1152 + 256 values) ----
    const int gid = bid * 128 + t;           // 0..4095
    for (int i = gid; i < BN * NP; i += 4096) {
        const int c = i - (i / NP) * NP;
        w_out[i] = bd[c];
    }
    if (gid < BN * NC) bias_out[gid] = bb[gid & 15] + dfn[gid & 15];
}

// ------------- kernel 2: dyn += h@Wd ; bias += h@Wb (k-split atomics) --------
// grid 72 blocks = 9 col-groups (128 cols) x 8 k-splits (32 k), 128 threads.
// h-slice [16][32] staged in LDS (wave-uniform broadcast); each thread owns one
// Wd column: per k, ONE coalesced Wd load feeds 16 FMAs (one per sample).
// Wd is read exactly once chip-wide. Partials combined via f32 atomicAdd into
// the pre-initialized w_out/bias_out.  [r12-proven, ~3 us]
__global__ __launch_bounds__(128) void k_dyn(const float* __restrict__ h_in,
                                             const float* __restrict__ Wd,
                                             const float* __restrict__ Wb,
                                             float* __restrict__ w_out,
                                             float* __restrict__ bias_out) {
    __shared__ float hs[16][32];
    const int bid = blockIdx.x;
    const int cg  = bid % 9;                 // column group (128 cols)
    const int ks  = bid / 9;                 // k-split (32 k)
    const int k0  = ks * 32;
    const int t   = threadIdx.x;

#pragma unroll
    for (int j = 0; j < 4; ++j) {
        const int idx = t + 128 * j;         // 0..511
        const int bi = idx >> 5, kk = idx & 31;
        hs[bi][kk] = h_in[bi * FF + k0 + kk];
    }
    __syncthreads();

    const int i = cg * 128 + t;              // output column < 1152
    float a[16];
#pragma unroll
    for (int b = 0; b < 16; ++b) a[b] = 0.0f;

#pragma unroll 8
    for (int kk = 0; kk < 32; ++kk) {
        const float w = Wd[(size_t)(k0 + kk) * NP + i];
#pragma unroll
        for (int b = 0; b < 16; ++b) a[b] = fmaf(hs[b][kk], w, a[b]);
    }
#pragma unroll
    for (int b = 0; b < 16; ++b) atomicAdd(&w_out[b * NP + i], a[b]);

    if (cg == 0) {                           // bias partials ride along here
#pragma unroll
        for (int r = 0; r < 2; ++r) {
            const int p = t + r * 128;       // 0..255
            const int b = p >> 4, c = p & 15;
            float s = 0.0f;
#pragma unroll 8
            for (int kk = 0; kk < 32; ++kk)
                s = fmaf(hs[b][kk], Wb[(size_t)(k0 + kk) * NC + c], s);
            atomicAdd(&bias_out[b * NC + c], s);
        }
    }
}

// ---------------- kernel 3: dynamic conv as per-sample MFMA GEMM -------------
// Round-8 validated body + 2x grid split + THREE independent accumulator
// chains (accM=hi*hi, accL=lo*hi, accH=hi*lo): dependent MFMA chain per tile
// is 3-deep, not 6. Each wave does 7 16-px tiles; 7 waves/SIMD of TLP.
// mfma_f32_16x16x32_bf16 layouts (lane l):
//   A: row = l&15 (pixel), k = (l>>4)*8 + i  -> one 32B NHWC load per chunk
//   B: col = l&15 (channel), k = (l>>4)*8+i  -> loaded once per wave (24 regs)
//   C: col = l&15 (channel), row = (l>>4)*4 + r (pixel)
__global__ __launch_bounds__(128) void k_conv(const float* __restrict__ in,
                                              const float* __restrict__ w_all,
                                              const float* __restrict__ bias_all,
                                              float* __restrict__ out) {
    const int b    = blockIdx.z;
    const int half = blockIdx.x;       // 0/1: tiles 0-6 or 7-13
    const int t    = threadIdx.x;
    const int wid  = t >> 6;
    const int lane = t & 63;
    const int cl   = lane & 15;        // A-row pixel idx / B,C channel idx
    const int g    = lane >> 4;        // k-group 0..3
    const int y    = blockIdx.y * 2 + wid;

    // ---- per-lane tap geometry for the 3 k-chunks ----
    int  dyL[3], dxL[3];
    bool real[3];
#pragma unroll
    for (int c = 0; c < 3; ++c) {
        const int tap = c * 4 + g;
        real[c] = (tap < 9);
        const int tp = real[c] ? tap : 0;
        dyL[c] = tp / 3;
        dxL[c] = tp - 3 * dyL[c];
    }

    // ---- B fragments (hi/lo), loaded once per wave ----
    const float* __restrict__ wq = w_all + b * NP;
    short8 bhi0, blo0, bhi1, blo1, bhi2, blo2;
    {
        float wv[8];
#pragma unroll
        for (int i = 0; i < 8; ++i)
            wv[i] = real[0] ? wq[(i * 9 + (0 * 4 + g)) * NC + cl] : 0.0f;
        split8(wv, bhi0, blo0);
#pragma unroll
        for (int i = 0; i < 8; ++i)
            wv[i] = real[1] ? wq[(i * 9 + (1 * 4 + g)) * NC + cl] : 0.0f;
        split8(wv, bhi1, blo1);
#pragma unroll
        for (int i = 0; i < 8; ++i)
            wv[i] = real[2] ? wq[(i * 9 + (2 * 4 + g)) * NC + cl] : 0.0f;
        split8(wv, bhi2, blo2);
    }

    // ---- per-chunk input row base + validity ----
    size_t ro[3];
    bool   okr[3];
#pragma unroll
    for (int c = 0; c < 3; ++c) {
        const int iy = y + dyL[c] - 1;
        okr[c] = real[c] && ((unsigned)iy < (unsigned)HH);
        const int iyc = min(max(iy, 0), HH - 1);
        ro[c] = ((size_t)(b * HH + iyc) * WW) * CI;
    }

    const float bias = bias_all[b * NC + cl];
    const size_t orow = ((size_t)(b * HH + y) * WW) * NC;

#pragma unroll 1
    for (int tx = 0; tx < 7; ++tx) {
        const int x0 = (half * 7 + tx) * 16;
        f32x4 accM = {bias, bias, bias, bias};   // hi*hi
        f32x4 accL = {0.f, 0.f, 0.f, 0.f};       // lo*hi
        f32x4 accH = {0.f, 0.f, 0.f, 0.f};       // hi*lo

#pragma unroll
        for (int c = 0; c < 3; ++c) {
            const int  ix = x0 + cl + dxL[c] - 1;
            const bool ok = okr[c] && ((unsigned)ix < (unsigned)WW);
            const int  ixc = min(max(ix, 0), WW - 1);
            const float4* pp = (const float4*)(in + ro[c] + (size_t)ixc * CI);
            const float4 a0 = pp[0];
            const float4 a1 = pp[1];
            float av[8];
            av[0] = ok ? a0.x : 0.0f;
            av[1] = ok ? a0.y : 0.0f;
            av[2] = ok ? a0.z : 0.0f;
            av[3] = ok ? a0.w : 0.0f;
            av[4] = ok ? a1.x : 0.0f;
            av[5] = ok ? a1.y : 0.0f;
            av[6] = ok ? a1.z : 0.0f;
            av[7] = ok ? a1.w : 0.0f;
            short8 ahi, alo;
            split8(av, ahi, alo);
            const short8 bh = (c == 0) ? bhi0 : (c == 1) ? bhi1 : bhi2;
            const short8 bl = (c == 0) ? blo0 : (c == 1) ? blo1 : blo2;
            accM = __builtin_amdgcn_mfma_f32_16x16x32_bf16(ahi, bh, accM, 0, 0, 0);
            accL = __builtin_amdgcn_mfma_f32_16x16x32_bf16(alo, bh, accL, 0, 0, 0);
            accH = __builtin_amdgcn_mfma_f32_16x16x32_bf16(ahi, bl, accH, 0, 0, 0);
        }

        // ---- epilogue: elu + store (lane cl = channel, rows g*4+r = pixel) --
#pragma unroll
        for (int r = 0; r < 4; ++r) {
            const int px = g * 4 + r;
            out[orow + (size_t)(x0 + px) * NC + cl] =
                elu_f(accM[r] + accL[r] + accH[r]);
        }
    }
}

extern "C" void kernel_launch(void* const* d_in, const int* in_sizes, int n_in,
                              void* d_out, int out_size, void* d_ws, size_t ws_size,
                              hipStream_t stream) {
    const float* inpt = (const float*)d_in[0];
    const float* fi   = (const float*)d_in[1];
    const float* W1   = (const float*)d_in[2];
    const float* b1   = (const float*)d_in[3];
    const float* Wd   = (const float*)d_in[4];
    const float* bd   = (const float*)d_in[5];
    const float* Wb   = (const float*)d_in[6];
    const float* bb   = (const float*)d_in[7];
    const float* dfn  = (const float*)d_in[8];
    float* out = (float*)d_out;

    float* ws    = (float*)d_ws;
    float* h     = ws;                    // 16*256   = 4096 floats
    float* wDyn  = ws + 4096;             // 16*1152  = 18432 floats
    float* biasA = ws + 4096 + 18432;     // 16*16    = 256 floats

    k_h  <<<32, 128, 0, stream>>>(fi, W1, b1, bd, bb, dfn, h, wDyn, biasA);
    k_dyn<<<72, 128, 0, stream>>>(h, Wd, Wb, wDyn, biasA);
    k_conv<<<dim3(2, 112, BN), 128, 0, stream>>>(inpt, wDyn, biasA, out);
}

// Round 15
// 46.061 us; speedup vs baseline: 1.2960x; 1.0007x over previous
//
#include <hip/hip_runtime.h>
#include <math.h>

// Problem constants
constexpr int BN  = 16;    // batch
constexpr int HH  = 224;
constexpr int WW  = 224;
constexpr int CI  = 8;     // input channels
constexpr int FF  = 256;   // filter feature dim
constexpr int NC  = 16;    // output channels
constexpr int NP  = 1152;  // CI*NC*3*3 dynamic params per sample
// reference patch index p = cin*9 + dy*3 + dx ; w[b][p][c] = dyn[b][p*16+c]
// MFMA K-ordering: k = tap*8 + cin, tap = dy*3+dx (taps 9..11 pad=0)

typedef __attribute__((ext_vector_type(8))) short short8;   // 8 bf16 = 4 VGPR
typedef __attribute__((ext_vector_type(4))) float f32x4;

__device__ __forceinline__ float elu_f(float x) {
    return x > 0.0f ? x : (__expf(x) - 1.0f);
}

// split f32 -> bf16 hi (truncate) + bf16 lo (residual, truncate): v ~= hi+lo
__device__ __forceinline__ void split8(const float* v, short8& hi, short8& lo) {
#pragma unroll
    for (int j = 0; j < 8; ++j) {
        const unsigned u = __float_as_uint(v[j]);
        hi[j] = (short)(u >> 16);
        const float hf = __uint_as_float(u & 0xffff0000u);
        lo[j] = (short)(__float_as_uint(v[j] - hf) >> 16);
    }
}

// ---------------- kernel 1: h = elu(filter_inpt @ W1 + b1) -------------------
// grid 32 blocks (16 samples x 2 halves), 128 threads. Also initializes
// w_out (=bd) and bias_out (=bb+dfn) for k_dyn's atomic k-split accumulation.
__global__ __launch_bounds__(128) void k_h(const float* __restrict__ fi,
                                           const float* __restrict__ W1,
                                           const float* __restrict__ b1,
                                           const float* __restrict__ bd,
                                           const float* __restrict__ bb,
                                           const float* __restrict__ dfn,
                                           float* __restrict__ h_out,
                                           float* __restrict__ w_out,
                                           float* __restrict__ bias_out) {
    __shared__ float x[FF];
    int bid = blockIdx.x;
    int b = bid >> 1, half = bid & 1;
    int t = threadIdx.x;
    x[t]       = fi[b * FF + t];
    x[t + 128] = fi[b * FF + t + 128];
    __syncthreads();
    int col = half * 128 + t;
    float acc = b1[col];
#pragma unroll 8
    for (int k = 0; k < FF; ++k) acc = fmaf(x[k], W1[k * FF + col], acc);
    h_out[b * FF + col] = elu_f(acc);

    // ---- init for k_dyn atomics ----
    const int gid = bid * 128 + t;           // 0..4095
    for (int i = gid; i < BN * NP; i += 4096) {
        const int c = i - (i / NP) * NP;
        w_out[i] = bd[c];
    }
    if (gid < BN * NC) bias_out[gid] = bb[gid & 15] + dfn[gid & 15];
}

// ------------- kernel 2: dyn += h@Wd ; bias += h@Wb (k-split atomics) --------
// grid 72 blocks = 9 col-groups x 8 k-splits, 128 threads. [r12-proven ~3 us]
__global__ __launch_bounds__(128) void k_dyn(const float* __restrict__ h_in,
                                             const float* __restrict__ Wd,
                                             const float* __restrict__ Wb,
                                             float* __restrict__ w_out,
                                             float* __restrict__ bias_out) {
    __shared__ float hs[16][32];
    const int bid = blockIdx.x;
    const int cg  = bid % 9;                 // column group (128 cols)
    const int ks  = bid / 9;                 // k-split (32 k)
    const int k0  = ks * 32;
    const int t   = threadIdx.x;

#pragma unroll
    for (int j = 0; j < 4; ++j) {
        const int idx = t + 128 * j;         // 0..511
        const int bi = idx >> 5, kk = idx & 31;
        hs[bi][kk] = h_in[bi * FF + k0 + kk];
    }
    __syncthreads();

    const int i = cg * 128 + t;              // output column < 1152
    float a[16];
#pragma unroll
    for (int b = 0; b < 16; ++b) a[b] = 0.0f;

#pragma unroll 8
    for (int kk = 0; kk < 32; ++kk) {
        const float w = Wd[(size_t)(k0 + kk) * NP + i];
#pragma unroll
        for (int b = 0; b < 16; ++b) a[b] = fmaf(hs[b][kk], w, a[b]);
    }
#pragma unroll
    for (int b = 0; b < 16; ++b) atomicAdd(&w_out[b * NP + i], a[b]);

    if (cg == 0) {                           // bias partials ride along here
#pragma unroll
        for (int r = 0; r < 2; ++r) {
            const int p = t + r * 128;       // 0..255
            const int b = p >> 4, c = p & 15;
            float s = 0.0f;
#pragma unroll 8
            for (int kk = 0; kk < 32; ++kk)
                s = fmaf(hs[b][kk], Wb[(size_t)(k0 + kk) * NC + c], s);
            atomicAdd(&bias_out[b * NC + c], s);
        }
    }
}

// ---------------- kernel 3: dynamic conv as per-sample MFMA GEMM -------------
// r14 body + (a) 1-tile software prefetch: tile tx+1's 6 A-loads issue BEFORE
// tile tx's split/MFMA and are pinned by sched_barrier(0) -> load latency is
// covered by a full iteration of work; (b) bijective XCD swizzle: each XCD
// owns 2 whole samples (3.2 MB ~ its 4 MB L2) so the 3x input row re-reads
// become L2 hits. Named prefetch registers (no arrays -> no spill trigger).
// mfma_f32_16x16x32_bf16 layouts (lane l):
//   A: row = l&15 (pixel), k = (l>>4)*8 + i ; B: col = l&15, same k
//   C: col = l&15 (channel), row = (l>>4)*4 + r (pixel)
__global__ __launch_bounds__(128) void k_conv(const float* __restrict__ in,
                                              const float* __restrict__ w_all,
                                              const float* __restrict__ bias_all,
                                              float* __restrict__ out) {
    // ---- bijective XCD swizzle (nwg = 3584 = 8*448; 448 = 2 samples) ----
    const int hid = blockIdx.x + 2 * (blockIdx.y + 112 * blockIdx.z);
    const int lid = (hid & 7) * 448 + (hid >> 3);
    const int b    = lid / 224;
    const int rem  = lid - b * 224;
    const int yblk = rem >> 1;
    const int half = rem & 1;

    const int t    = threadIdx.x;
    const int wid  = t >> 6;
    const int lane = t & 63;
    const int cl   = lane & 15;        // A-row pixel idx / B,C channel idx
    const int g    = lane >> 4;        // k-group 0..3
    const int y    = yblk * 2 + wid;

    // ---- per-lane tap geometry for the 3 k-chunks ----
    int  dyL[3], dxL[3];
    bool real[3];
#pragma unroll
    for (int c = 0; c < 3; ++c) {
        const int tap = c * 4 + g;
        real[c] = (tap < 9);
        const int tp = real[c] ? tap : 0;
        dyL[c] = tp / 3;
        dxL[c] = tp - 3 * dyL[c];
    }

    // ---- B fragments (hi/lo), loaded once per wave ----
    const float* __restrict__ wq = w_all + b * NP;
    short8 bhi0, blo0, bhi1, blo1, bhi2, blo2;
    {
        float wv[8];
#pragma unroll
        for (int i = 0; i < 8; ++i)
            wv[i] = real[0] ? wq[(i * 9 + (0 * 4 + g)) * NC + cl] : 0.0f;
        split8(wv, bhi0, blo0);
#pragma unroll
        for (int i = 0; i < 8; ++i)
            wv[i] = real[1] ? wq[(i * 9 + (1 * 4 + g)) * NC + cl] : 0.0f;
        split8(wv, bhi1, blo1);
#pragma unroll
        for (int i = 0; i < 8; ++i)
            wv[i] = real[2] ? wq[(i * 9 + (2 * 4 + g)) * NC + cl] : 0.0f;
        split8(wv, bhi2, blo2);
    }

    // ---- per-chunk input row base + validity ----
    size_t ro[3];
    bool   okr[3];
#pragma unroll
    for (int c = 0; c < 3; ++c) {
        const int iy = y + dyL[c] - 1;
        okr[c] = real[c] && ((unsigned)iy < (unsigned)HH);
        const int iyc = min(max(iy, 0), HH - 1);
        ro[c] = ((size_t)(b * HH + iyc) * WW) * CI;
    }

    const float bias = bias_all[b * NC + cl];
    const size_t orow = ((size_t)(b * HH + y) * WW) * NC;

    // ---- prefetch tile 0 (clamped addresses; masking applied at use) ----
    float4 a00, a01, a10, a11, a20, a21;
    {
        const int x0 = (half * 7) * 16;
#pragma unroll
        for (int c = 0; c < 3; ++c) {
            const int ix  = x0 + cl + dxL[c] - 1;
            const int ixc = min(max(ix, 0), WW - 1);
            const float4* pp = (const float4*)(in + ro[c] + (size_t)ixc * CI);
            if (c == 0) { a00 = pp[0]; a01 = pp[1]; }
            if (c == 1) { a10 = pp[0]; a11 = pp[1]; }
            if (c == 2) { a20 = pp[0]; a21 = pp[1]; }
        }
    }

#pragma unroll 1
    for (int tx = 0; tx < 7; ++tx) {
        const int x0  = (half * 7 + tx) * 16;
        const int txn = (tx < 6) ? tx + 1 : 6;          // clamped next tile
        const int x0n = (half * 7 + txn) * 16;

        // current tile data moves to use-registers (SSA rename, no copies)
        const float4 u00 = a00, u01 = a01;
        const float4 u10 = a10, u11 = a11;
        const float4 u20 = a20, u21 = a21;

        // ---- issue next tile's 6 loads (pinned before the compute) ----
        {
            const int ix  = x0n + cl + dxL[0] - 1;
            const int ixc = min(max(ix, 0), WW - 1);
            const float4* pp = (const float4*)(in + ro[0] + (size_t)ixc * CI);
            a00 = pp[0]; a01 = pp[1];
        }
        {
            const int ix  = x0n + cl + dxL[1] - 1;
            const int ixc = min(max(ix, 0), WW - 1);
            const float4* pp = (const float4*)(in + ro[1] + (size_t)ixc * CI);
            a10 = pp[0]; a11 = pp[1];
        }
        {
            const int ix  = x0n + cl + dxL[2] - 1;
            const int ixc = min(max(ix, 0), WW - 1);
            const float4* pp = (const float4*)(in + ro[2] + (size_t)ixc * CI);
            a20 = pp[0]; a21 = pp[1];
        }
        __builtin_amdgcn_sched_barrier(0);

        f32x4 accM = {bias, bias, bias, bias};   // hi*hi
        f32x4 accL = {0.f, 0.f, 0.f, 0.f};       // lo*hi
        f32x4 accH = {0.f, 0.f, 0.f, 0.f};       // hi*lo

#pragma unroll
        for (int c = 0; c < 3; ++c) {
            const int  ix = x0 + cl + dxL[c] - 1;
            const bool ok = okr[c] && ((unsigned)ix < (unsigned)WW);
            const float4 v0 = (c == 0) ? u00 : (c == 1) ? u10 : u20;
            const float4 v1 = (c == 0) ? u01 : (c == 1) ? u11 : u21;
            float av[8];
            av[0] = ok ? v0.x : 0.0f;
            av[1] = ok ? v0.y : 0.0f;
            av[2] = ok ? v0.z : 0.0f;
            av[3] = ok ? v0.w : 0.0f;
            av[4] = ok ? v1.x : 0.0f;
            av[5] = ok ? v1.y : 0.0f;
            av[6] = ok ? v1.z : 0.0f;
            av[7] = ok ? v1.w : 0.0f;
            short8 ahi, alo;
            split8(av, ahi, alo);
            const short8 bh = (c == 0) ? bhi0 : (c == 1) ? bhi1 : bhi2;
            const short8 bl = (c == 0) ? blo0 : (c == 1) ? blo1 : blo2;
            accM = __builtin_amdgcn_mfma_f32_16x16x32_bf16(ahi, bh, accM, 0, 0, 0);
            accL = __builtin_amdgcn_mfma_f32_16x16x32_bf16(alo, bh, accL, 0, 0, 0);
            accH = __builtin_amdgcn_mfma_f32_16x16x32_bf16(ahi, bl, accH, 0, 0, 0);
        }

        // ---- epilogue: elu + store (lane cl = channel, rows g*4+r = pixel) --
#pragma unroll
        for (int r = 0; r < 4; ++r) {
            const int px = g * 4 + r;
            out[orow + (size_t)(x0 + px) * NC + cl] =
                elu_f(accM[r] + accL[r] + accH[r]);
        }
    }
}

extern "C" void kernel_launch(void* const* d_in, const int* in_sizes, int n_in,
                              void* d_out, int out_size, void* d_ws, size_t ws_size,
                              hipStream_t stream) {
    const float* inpt = (const float*)d_in[0];
    const float* fi   = (const float*)d_in[1];
    const float* W1   = (const float*)d_in[2];
    const float* b1   = (const float*)d_in[3];
    const float* Wd   = (const float*)d_in[4];
    const float* bd   = (const float*)d_in[5];
    const float* Wb   = (const float*)d_in[6];
    const float* bb   = (const float*)d_in[7];
    const float* dfn  = (const float*)d_in[8];
    float* out = (float*)d_out;

    float* ws    = (float*)d_ws;
    float* h     = ws;                    // 16*256   = 4096 floats
    float* wDyn  = ws + 4096;             // 16*1152  = 18432 floats
    float* biasA = ws + 4096 + 18432;     // 16*16    = 256 floats

    k_h  <<<32, 128, 0, stream>>>(fi, W1, b1, bd, bb, dfn, h, wDyn, biasA);
    k_dyn<<<72, 128, 0, stream>>>(h, Wd, Wb, wDyn, biasA);
    k_conv<<<dim3(2, 112, BN), 128, 0, stream>>>(inpt, wDyn, biasA, out);
}

// Round 16
// 40.037 us; speedup vs baseline: 1.4910x; 1.1505x over previous
//
#include <hip/hip_runtime.h>
#include <math.h>

// Problem constants
constexpr int BN  = 16;    // batch
constexpr int HH  = 224;
constexpr int WW  = 224;
constexpr int CI  = 8;     // input channels
constexpr int FF  = 256;   // filter feature dim
constexpr int NC  = 16;    // output channels
constexpr int NP  = 1152;  // CI*NC*3*3 dynamic params per sample
// reference patch index p = cin*9 + dy*3 + dx ; w[b][p][c] = dyn[b][p*16+c]
// MFMA K-ordering: k = tap*8 + cin, tap = dy*3+dx (taps 9..11 pad=0)

typedef __attribute__((ext_vector_type(8))) short short8;   // 8 bf16 = 4 VGPR
typedef __attribute__((ext_vector_type(4))) float f32x4;

__device__ __forceinline__ float elu_f(float x) {
    return x > 0.0f ? x : (__expf(x) - 1.0f);
}

// split f32 -> bf16 hi (truncate) + bf16 lo (residual, truncate): v ~= hi+lo
__device__ __forceinline__ void split8(const float* v, short8& hi, short8& lo) {
#pragma unroll
    for (int j = 0; j < 8; ++j) {
        const unsigned u = __float_as_uint(v[j]);
        hi[j] = (short)(u >> 16);
        const float hf = __uint_as_float(u & 0xffff0000u);
        lo[j] = (short)(__float_as_uint(v[j] - hf) >> 16);
    }
}

// -------- kernel 1: h partials, k-split x4 (hp[ks][b][col], pre-elu) ---------
// grid 128 blocks = (b, half, ks), 128 threads. Each block: 64-k partial of
// fi@W1 (+b1 on ks==0). 4x more blocks, 4x shorter load chain than the old
// k_h (which was ~6 us of pipelined-L2 latency at 32 blocks). No atomics:
// k_dyn sums the 4 partials when staging. Also initializes w_out (=bd) and
// bias_out (=bb+dfn) for k_dyn's atomic accumulation.
__global__ __launch_bounds__(128) void k_h(const float* __restrict__ fi,
                                           const float* __restrict__ W1,
                                           const float* __restrict__ b1,
                                           const float* __restrict__ bd,
                                           const float* __restrict__ bb,
                                           const float* __restrict__ dfn,
                                           float* __restrict__ hp,
                                           float* __restrict__ w_out,
                                           float* __restrict__ bias_out) {
    __shared__ float x[64];
    const int bid  = blockIdx.x;
    const int b    = bid >> 3;
    const int half = (bid >> 2) & 1;
    const int ks   = bid & 3;
    const int t    = threadIdx.x;

    if (t < 64) x[t] = fi[b * FF + ks * 64 + t];
    __syncthreads();

    const int col = half * 128 + t;
    float acc = (ks == 0) ? b1[col] : 0.0f;
#pragma unroll 8
    for (int k = 0; k < 64; ++k)
        acc = fmaf(x[k], W1[(ks * 64 + k) * FF + col], acc);
    hp[(ks * BN + b) * FF + col] = acc;

    // ---- init for k_dyn atomics (grid-stride over 16*1152 + 256 values) ----
    const int gid = bid * 128 + t;           // 0..16383
    for (int i = gid; i < BN * NP; i += 16384) {
        const int c = i - (i / NP) * NP;
        w_out[i] = bd[c];
    }
    if (gid < BN * NC) bias_out[gid] = bb[gid & 15] + dfn[gid & 15];
}

// ------------- kernel 2: dyn += h@Wd ; bias += h@Wb (k-split atomics) --------
// grid 72 blocks = 9 col-groups x 8 k-splits, 128 threads. [r12-proven ~3 us]
// Stages hs = elu(sum of the 4 h-partials) for its 32-k slice.
__global__ __launch_bounds__(128) void k_dyn(const float* __restrict__ hp,
                                             const float* __restrict__ Wd,
                                             const float* __restrict__ Wb,
                                             float* __restrict__ w_out,
                                             float* __restrict__ bias_out) {
    __shared__ float hs[16][32];
    const int bid = blockIdx.x;
    const int cg  = bid % 9;                 // column group (128 cols)
    const int ks  = bid / 9;                 // k-split (32 k)
    const int k0  = ks * 32;
    const int t   = threadIdx.x;

#pragma unroll
    for (int j = 0; j < 4; ++j) {
        const int idx = t + 128 * j;         // 0..511
        const int bi = idx >> 5, kk = idx & 31;
        const int o = bi * FF + k0 + kk;
        const float s = hp[o] + hp[BN * FF + o] +
                        hp[2 * BN * FF + o] + hp[3 * BN * FF + o];
        hs[bi][kk] = elu_f(s);
    }
    __syncthreads();

    const int i = cg * 128 + t;              // output column < 1152
    float a[16];
#pragma unroll
    for (int b = 0; b < 16; ++b) a[b] = 0.0f;

#pragma unroll 8
    for (int kk = 0; kk < 32; ++kk) {
        const float w = Wd[(size_t)(k0 + kk) * NP + i];
#pragma unroll
        for (int b = 0; b < 16; ++b) a[b] = fmaf(hs[b][kk], w, a[b]);
    }
#pragma unroll
    for (int b = 0; b < 16; ++b) atomicAdd(&w_out[b * NP + i], a[b]);

    if (cg == 0) {                           // bias partials ride along here
#pragma unroll
        for (int r = 0; r < 2; ++r) {
            const int p = t + r * 128;       // 0..255
            const int b = p >> 4, c = p & 15;
            float s = 0.0f;
#pragma unroll 8
            for (int kk = 0; kk < 32; ++kk)
                s = fmaf(hs[b][kk], Wb[(size_t)(k0 + kk) * NC + c], s);
            atomicAdd(&bias_out[b * NC + c], s);
        }
    }
}

// ---------------- kernel 3: dynamic conv as per-sample MFMA GEMM -------------
// r14 proven body (46.1/45.9 us family): 2x grid split, 3 independent
// accumulator chains. Each wave does 7 16-px tiles; 7 waves/SIMD of TLP.
// mfma_f32_16x16x32_bf16 layouts (lane l):
//   A: row = l&15 (pixel), k = (l>>4)*8 + i  -> one 32B NHWC load per chunk
//   B: col = l&15 (channel), k = (l>>4)*8+i  -> loaded once per wave (24 regs)
//   C: col = l&15 (channel), row = (l>>4)*4 + r (pixel)
__global__ __launch_bounds__(128) void k_conv(const float* __restrict__ in,
                                              const float* __restrict__ w_all,
                                              const float* __restrict__ bias_all,
                                              float* __restrict__ out) {
    const int b    = blockIdx.z;
    const int half = blockIdx.x;       // 0/1: tiles 0-6 or 7-13
    const int t    = threadIdx.x;
    const int wid  = t >> 6;
    const int lane = t & 63;
    const int cl   = lane & 15;        // A-row pixel idx / B,C channel idx
    const int g    = lane >> 4;        // k-group 0..3
    const int y    = blockIdx.y * 2 + wid;

    // ---- per-lane tap geometry for the 3 k-chunks ----
    int  dyL[3], dxL[3];
    bool real[3];
#pragma unroll
    for (int c = 0; c < 3; ++c) {
        const int tap = c * 4 + g;
        real[c] = (tap < 9);
        const int tp = real[c] ? tap : 0;
        dyL[c] = tp / 3;
        dxL[c] = tp - 3 * dyL[c];
    }

    // ---- B fragments (hi/lo), loaded once per wave ----
    const float* __restrict__ wq = w_all + b * NP;
    short8 bhi0, blo0, bhi1, blo1, bhi2, blo2;
    {
        float wv[8];
#pragma unroll
        for (int i = 0; i < 8; ++i)
            wv[i] = real[0] ? wq[(i * 9 + (0 * 4 + g)) * NC + cl] : 0.0f;
        split8(wv, bhi0, blo0);
#pragma unroll
        for (int i = 0; i < 8; ++i)
            wv[i] = real[1] ? wq[(i * 9 + (1 * 4 + g)) * NC + cl] : 0.0f;
        split8(wv, bhi1, blo1);
#pragma unroll
        for (int i = 0; i < 8; ++i)
            wv[i] = real[2] ? wq[(i * 9 + (2 * 4 + g)) * NC + cl] : 0.0f;
        split8(wv, bhi2, blo2);
    }

    // ---- per-chunk input row base + validity ----
    size_t ro[3];
    bool   okr[3];
#pragma unroll
    for (int c = 0; c < 3; ++c) {
        const int iy = y + dyL[c] - 1;
        okr[c] = real[c] && ((unsigned)iy < (unsigned)HH);
        const int iyc = min(max(iy, 0), HH - 1);
        ro[c] = ((size_t)(b * HH + iyc) * WW) * CI;
    }

    const float bias = bias_all[b * NC + cl];
    const size_t orow = ((size_t)(b * HH + y) * WW) * NC;

#pragma unroll 1
    for (int tx = 0; tx < 7; ++tx) {
        const int x0 = (half * 7 + tx) * 16;
        f32x4 accM = {bias, bias, bias, bias};   // hi*hi
        f32x4 accL = {0.f, 0.f, 0.f, 0.f};       // lo*hi
        f32x4 accH = {0.f, 0.f, 0.f, 0.f};       // hi*lo

#pragma unroll
        for (int c = 0; c < 3; ++c) {
            const int  ix = x0 + cl + dxL[c] - 1;
            const bool ok = okr[c] && ((unsigned)ix < (unsigned)WW);
            const int  ixc = min(max(ix, 0), WW - 1);
            const float4* pp = (const float4*)(in + ro[c] + (size_t)ixc * CI);
            const float4 a0 = pp[0];
            const float4 a1 = pp[1];
            float av[8];
            av[0] = ok ? a0.x : 0.0f;
            av[1] = ok ? a0.y : 0.0f;
            av[2] = ok ? a0.z : 0.0f;
            av[3] = ok ? a0.w : 0.0f;
            av[4] = ok ? a1.x : 0.0f;
            av[5] = ok ? a1.y : 0.0f;
            av[6] = ok ? a1.z : 0.0f;
            av[7] = ok ? a1.w : 0.0f;
            short8 ahi, alo;
            split8(av, ahi, alo);
            const short8 bh = (c == 0) ? bhi0 : (c == 1) ? bhi1 : bhi2;
            const short8 bl = (c == 0) ? blo0 : (c == 1) ? blo1 : blo2;
            accM = __builtin_amdgcn_mfma_f32_16x16x32_bf16(ahi, bh, accM, 0, 0, 0);
            accL = __builtin_amdgcn_mfma_f32_16x16x32_bf16(alo, bh, accL, 0, 0, 0);
            accH = __builtin_amdgcn_mfma_f32_16x16x32_bf16(ahi, bl, accH, 0, 0, 0);
        }

        // ---- epilogue: elu + store (lane cl = channel, rows g*4+r = pixel) --
#pragma unroll
        for (int r = 0; r < 4; ++r) {
            const int px = g * 4 + r;
            out[orow + (size_t)(x0 + px) * NC + cl] =
                elu_f(accM[r] + accL[r] + accH[r]);
        }
    }
}

extern "C" void kernel_launch(void* const* d_in, const int* in_sizes, int n_in,
                              void* d_out, int out_size, void* d_ws, size_t ws_size,
                              hipStream_t stream) {
    const float* inpt = (const float*)d_in[0];
    const float* fi   = (const float*)d_in[1];
    const float* W1   = (const float*)d_in[2];
    const float* b1   = (const float*)d_in[3];
    const float* Wd   = (const float*)d_in[4];
    const float* bd   = (const float*)d_in[5];
    const float* Wb   = (const float*)d_in[6];
    const float* bb   = (const float*)d_in[7];
    const float* dfn  = (const float*)d_in[8];
    float* out = (float*)d_out;

    float* ws    = (float*)d_ws;
    float* hp    = ws;                        // 4*16*256 = 16384 floats
    float* wDyn  = ws + 16384;                // 16*1152  = 18432 floats
    float* biasA = ws + 16384 + 18432;        // 16*16    = 256 floats

    k_h  <<<128, 128, 0, stream>>>(fi, W1, b1, bd, bb, dfn, hp, wDyn, biasA);
    k_dyn<<<72, 128, 0, stream>>>(hp, Wd, Wb, wDyn, biasA);
    k_conv<<<dim3(2, 112, BN), 128, 0, stream>>>(inpt, wDyn, biasA, out);
}

// Round 17
// 39.731 us; speedup vs baseline: 1.5025x; 1.0077x over previous
//
#include <hip/hip_runtime.h>
#include <math.h>

// Problem constants
constexpr int BN  = 16;    // batch
constexpr int HH  = 224;
constexpr int WW  = 224;
constexpr int CI  = 8;     // input channels
constexpr int FF  = 256;   // filter feature dim
constexpr int NC  = 16;    // output channels
constexpr int NP  = 1152;  // CI*NC*3*3 dynamic params per sample
// reference patch index p = cin*9 + dy*3 + dx ; w[b][p][c] = dyn[b][p*16+c]
// MFMA K-ordering: k = tap*8 + cin, tap = dy*3+dx (taps 9..11 pad=0)

typedef __attribute__((ext_vector_type(8))) short short8;   // 8 bf16 = 4 VGPR
typedef __attribute__((ext_vector_type(4))) float f32x4;

__device__ __forceinline__ float elu_f(float x) {
    return x > 0.0f ? x : (__expf(x) - 1.0f);
}

// split f32 -> bf16 hi (truncate) + bf16 lo (residual, truncate): v ~= hi+lo
__device__ __forceinline__ void split8(const float* v, short8& hi, short8& lo) {
#pragma unroll
    for (int j = 0; j < 8; ++j) {
        const unsigned u = __float_as_uint(v[j]);
        hi[j] = (short)(u >> 16);
        const float hf = __uint_as_float(u & 0xffff0000u);
        lo[j] = (short)(__float_as_uint(v[j] - hf) >> 16);
    }
}

// -------- kernel 1: h partials, k-split x4 (hp[ks][b][col], pre-elu) ---------
// [r16-proven] grid 128 blocks = (b, half, ks), 128 threads.
__global__ __launch_bounds__(128) void k_h(const float* __restrict__ fi,
                                           const float* __restrict__ W1,
                                           const float* __restrict__ b1,
                                           const float* __restrict__ bd,
                                           const float* __restrict__ bb,
                                           const float* __restrict__ dfn,
                                           float* __restrict__ hp,
                                           float* __restrict__ w_out,
                                           float* __restrict__ bias_out) {
    __shared__ float x[64];
    const int bid  = blockIdx.x;
    const int b    = bid >> 3;
    const int half = (bid >> 2) & 1;
    const int ks   = bid & 3;
    const int t    = threadIdx.x;

    if (t < 64) x[t] = fi[b * FF + ks * 64 + t];
    __syncthreads();

    const int col = half * 128 + t;
    float acc = (ks == 0) ? b1[col] : 0.0f;
#pragma unroll 8
    for (int k = 0; k < 64; ++k)
        acc = fmaf(x[k], W1[(ks * 64 + k) * FF + col], acc);
    hp[(ks * BN + b) * FF + col] = acc;

    // ---- init for k_dyn atomics ----
    const int gid = bid * 128 + t;           // 0..16383
    for (int i = gid; i < BN * NP; i += 16384) {
        const int c = i - (i / NP) * NP;
        w_out[i] = bd[c];
    }
    if (gid < BN * NC) bias_out[gid] = bb[gid & 15] + dfn[gid & 15];
}

// ------------- kernel 2: dyn += h@Wd ; bias += h@Wb (k-split atomics) --------
// [r12/r16-proven] grid 72 blocks = 9 col-groups x 8 k-splits, 128 threads.
__global__ __launch_bounds__(128) void k_dyn(const float* __restrict__ hp,
                                             const float* __restrict__ Wd,
                                             const float* __restrict__ Wb,
                                             float* __restrict__ w_out,
                                             float* __restrict__ bias_out) {
    __shared__ float hs[16][32];
    const int bid = blockIdx.x;
    const int cg  = bid % 9;                 // column group (128 cols)
    const int ks  = bid / 9;                 // k-split (32 k)
    const int k0  = ks * 32;
    const int t   = threadIdx.x;

#pragma unroll
    for (int j = 0; j < 4; ++j) {
        const int idx = t + 128 * j;         // 0..511
        const int bi = idx >> 5, kk = idx & 31;
        const int o = bi * FF + k0 + kk;
        const float s = hp[o] + hp[BN * FF + o] +
                        hp[2 * BN * FF + o] + hp[3 * BN * FF + o];
        hs[bi][kk] = elu_f(s);
    }
    __syncthreads();

    const int i = cg * 128 + t;              // output column < 1152
    float a[16];
#pragma unroll
    for (int b = 0; b < 16; ++b) a[b] = 0.0f;

#pragma unroll 8
    for (int kk = 0; kk < 32; ++kk) {
        const float w = Wd[(size_t)(k0 + kk) * NP + i];
#pragma unroll
        for (int b = 0; b < 16; ++b) a[b] = fmaf(hs[b][kk], w, a[b]);
    }
#pragma unroll
    for (int b = 0; b < 16; ++b) atomicAdd(&w_out[b * NP + i], a[b]);

    if (cg == 0) {                           // bias partials ride along here
#pragma unroll
        for (int r = 0; r < 2; ++r) {
            const int p = t + r * 128;       // 0..255
            const int b = p >> 4, c = p & 15;
            float s = 0.0f;
#pragma unroll 8
            for (int kk = 0; kk < 32; ++kk)
                s = fmaf(hs[b][kk], Wb[(size_t)(k0 + kk) * NC + c], s);
            atomicAdd(&bias_out[b * NC + c], s);
        }
    }
}

// ---------------- kernel 3: dynamic conv as per-sample MFMA GEMM -------------
// LDS-staged version: block stages 4 rows x 114 px of input into LDS as
// PRE-SPLIT hi/lo bf16 (mask + split8 done ONCE per pixel). The tile loop is
// pure ds_read_b128 + MFMA (no masks, no split VALU). Global A-traffic drops
// ~5.7x (301 -> 52 MB/pass).
// OPERAND SWAP: weights passed as MFMA A-operand, patches as B (fragment lane
// mappings are identical, register contents unchanged). C becomes [ch][px]:
// lane (g,cl) holds channels g*4..g*4+3 of pixel x0+cl -> ONE float4 store.
// Zero weights on pad taps (real[]=false) carry the zeroing formerly done by
// A-masks.
__global__ __launch_bounds__(128) void k_conv(const float* __restrict__ in,
                                              const float* __restrict__ w_all,
                                              const float* __restrict__ bias_all,
                                              float* __restrict__ out) {
    __shared__ short8 lsA[4][116][2];        // [row][px][hi/lo] = 14,848 B

    const int b    = blockIdx.z;
    const int half = blockIdx.x;             // 0/1: x-half of the rows
    const int t    = threadIdx.x;
    const int wid  = t >> 6;
    const int lane = t & 63;
    const int cl   = lane & 15;
    const int g    = lane >> 4;              // k-group 0..3
    const int yb0  = blockIdx.y * 2;
    const int xb0  = half * 112;

    // ---- stage 4 rows x 114 px (hi/lo pre-split, zero-filled halo) ----
    for (int s = t; s < 456; s += 128) {
        const int r  = s / 114;
        const int j  = s - r * 114;
        const int gy = yb0 - 1 + r;
        const int gx = xb0 - 1 + j;
        const bool ok = ((unsigned)gy < (unsigned)HH) &&
                        ((unsigned)gx < (unsigned)WW);
        float av[8] = {0.f, 0.f, 0.f, 0.f, 0.f, 0.f, 0.f, 0.f};
        if (ok) {
            const float4* pp =
                (const float4*)(in + ((size_t)(b * HH + gy) * WW + gx) * CI);
            const float4 a0 = pp[0];
            const float4 a1 = pp[1];
            av[0] = a0.x; av[1] = a0.y; av[2] = a0.z; av[3] = a0.w;
            av[4] = a1.x; av[5] = a1.y; av[6] = a1.z; av[7] = a1.w;
        }
        short8 hi, lo;
        split8(av, hi, lo);
        lsA[r][j][0] = hi;
        lsA[r][j][1] = lo;
    }

    // ---- per-lane tap geometry for the 3 k-chunks ----
    int  dyL[3], dxL[3];
    bool real[3];
#pragma unroll
    for (int c = 0; c < 3; ++c) {
        const int tap = c * 4 + g;
        real[c] = (tap < 9);
        const int tp = real[c] ? tap : 0;
        dyL[c] = tp / 3;
        dxL[c] = tp - 3 * dyL[c];
    }

    // ---- weight fragments (hi/lo), loaded once per wave ----
    const float* __restrict__ wq = w_all + b * NP;
    short8 bhi0, blo0, bhi1, blo1, bhi2, blo2;
    {
        float wv[8];
#pragma unroll
        for (int i = 0; i < 8; ++i)
            wv[i] = real[0] ? wq[(i * 9 + (0 * 4 + g)) * NC + cl] : 0.0f;
        split8(wv, bhi0, blo0);
#pragma unroll
        for (int i = 0; i < 8; ++i)
            wv[i] = real[1] ? wq[(i * 9 + (1 * 4 + g)) * NC + cl] : 0.0f;
        split8(wv, bhi1, blo1);
#pragma unroll
        for (int i = 0; i < 8; ++i)
            wv[i] = real[2] ? wq[(i * 9 + (2 * 4 + g)) * NC + cl] : 0.0f;
        split8(wv, bhi2, blo2);
    }

    __syncthreads();

    // acc rows are channels g*4+r now -> bias is a per-lane float4
    const float4 bias4 = ((const float4*)(bias_all + b * NC))[g];
    const int y = yb0 + wid;
    const size_t orow = ((size_t)(b * HH + y) * WW) * NC;

#pragma unroll 1
    for (int tx = 0; tx < 7; ++tx) {
        const int x0 = xb0 + tx * 16;
        f32x4 accM = {bias4.x, bias4.y, bias4.z, bias4.w};   // hi*hi
        f32x4 accL = {0.f, 0.f, 0.f, 0.f};                   // hiW*loA
        f32x4 accH = {0.f, 0.f, 0.f, 0.f};                   // loW*hiA

#pragma unroll
        for (int c = 0; c < 3; ++c) {
            const int j = tx * 16 + cl + dxL[c];             // 0..113
            const int r = wid + dyL[c];                      // 0..3
            const short8 ahi = lsA[r][j][0];
            const short8 alo = lsA[r][j][1];
            const short8 bh = (c == 0) ? bhi0 : (c == 1) ? bhi1 : bhi2;
            const short8 bl = (c == 0) ? blo0 : (c == 1) ? blo1 : blo2;
            accM = __builtin_amdgcn_mfma_f32_16x16x32_bf16(bh, ahi, accM, 0, 0, 0);
            accL = __builtin_amdgcn_mfma_f32_16x16x32_bf16(bh, alo, accL, 0, 0, 0);
            accH = __builtin_amdgcn_mfma_f32_16x16x32_bf16(bl, ahi, accH, 0, 0, 0);
        }

        // ---- epilogue: elu + ONE float4 store (4 channels of pixel x0+cl) --
        float4 res;
        res.x = elu_f(accM[0] + accL[0] + accH[0]);
        res.y = elu_f(accM[1] + accL[1] + accH[1]);
        res.z = elu_f(accM[2] + accL[2] + accH[2]);
        res.w = elu_f(accM[3] + accL[3] + accH[3]);
        ((float4*)(out + orow + (size_t)(x0 + cl) * NC))[g] = res;
    }
}

extern "C" void kernel_launch(void* const* d_in, const int* in_sizes, int n_in,
                              void* d_out, int out_size, void* d_ws, size_t ws_size,
                              hipStream_t stream) {
    const float* inpt = (const float*)d_in[0];
    const float* fi   = (const float*)d_in[1];
    const float* W1   = (const float*)d_in[2];
    const float* b1   = (const float*)d_in[3];
    const float* Wd   = (const float*)d_in[4];
    const float* bd   = (const float*)d_in[5];
    const float* Wb   = (const float*)d_in[6];
    const float* bb   = (const float*)d_in[7];
    const float* dfn  = (const float*)d_in[8];
    float* out = (float*)d_out;

    float* ws    = (float*)d_ws;
    float* hp    = ws;                        // 4*16*256 = 16384 floats
    float* wDyn  = ws + 16384;                // 16*1152  = 18432 floats
    float* biasA = ws + 16384 + 18432;        // 16*16    = 256 floats

    k_h  <<<128, 128, 0, stream>>>(fi, W1, b1, bd, bb, dfn, hp, wDyn, biasA);
    k_dyn<<<72, 128, 0, stream>>>(hp, Wd, Wb, wDyn, biasA);
    k_conv<<<dim3(2, 112, BN), 128, 0, stream>>>(inpt, wDyn, biasA, out);
}